// Round 4
// baseline (436.124 us; speedup 1.0000x reference)
//
#include <hip/hip_runtime.h>
#include <stdint.h>

#define SEQ 1024
#define NB  1024
#define HD  64
#define BH  (NB*HD)            // elements per timestep plane
#define RPW 8                  // batch rows per wave (= per block)

typedef _Float16 f16x8 __attribute__((ext_vector_type(8)));
typedef float    f32x4 __attribute__((ext_vector_type(4)));
typedef uint32_t u32x4 __attribute__((ext_vector_type(4)));

#define L2E2 2.8853900817779268f   // 2*log2(e), folded into weights/bias

#if __has_builtin(__builtin_amdgcn_permlane32_swap) && __has_builtin(__builtin_amdgcn_permlane16_swap)
#define HAVE_PERMLANE 1
#else
#define HAVE_PERMLANE 0
#endif

template<int V> struct IC { static constexpr int value = V; };

__device__ __forceinline__ uint32_t pkrtz(float a, float b) {
    auto h = __builtin_amdgcn_cvt_pkrtz(a, b);
    return __builtin_bit_cast(uint32_t, h);
}
// weights prescaled by 2*log2(e): tanh(x) = 1 - 2/(exp2(2*log2e*x)+1)
__device__ __forceinline__ float tanh_scaled(float a2) {
    float e = __builtin_amdgcn_exp2f(a2);
    return 1.0f - 2.0f * __builtin_amdgcn_rcpf(e + 1.0f);
}

__global__ __launch_bounds__(64, 1) void rnn_kernel(
    const float* __restrict__ x,  const float* __restrict__ h0,
    const float* __restrict__ Wx, const float* __restrict__ bx,
    const float* __restrict__ Wh, const float* __restrict__ bh,
    float* __restrict__ out)
{
    const int lane = threadIdx.x;          // 0..63, single wave
    const int g    = lane >> 4;            // 16-lane group 0..3
    const int n    = lane & 15;            // MFMA col = batch row (valid < 8)
    const int nc   = n < RPW ? n : RPW - 1;
    const int R0   = blockIdx.x * RPW;
    const size_t xoff = (size_t)(R0 + nc) * HD + 8 * g;

    // ---- weights resident in VGPRs, prescaled (A-frag: row=n -> ch 16m+n, k=32T+8g+e) ----
    f16x8 whA[4][2], wxA[4][2];
    #pragma unroll
    for (int m = 0; m < 4; ++m) {
        #pragma unroll
        for (int T = 0; T < 2; ++T) {
            const float* wr = Wh + (size_t)(16*m + n) * HD + 32*T + 8*g;
            const float* xr = Wx + (size_t)(16*m + n) * HD + 32*T + 8*g;
            f32x4 wa = *(const f32x4*)wr, wb = *(const f32x4*)(wr + 4);
            f32x4 xa = *(const f32x4*)xr, xb = *(const f32x4*)(xr + 4);
            u32x4 dw, dx;
            dw[0]=pkrtz(wa[0]*L2E2, wa[1]*L2E2); dw[1]=pkrtz(wa[2]*L2E2, wa[3]*L2E2);
            dw[2]=pkrtz(wb[0]*L2E2, wb[1]*L2E2); dw[3]=pkrtz(wb[2]*L2E2, wb[3]*L2E2);
            dx[0]=pkrtz(xa[0]*L2E2, xa[1]*L2E2); dx[1]=pkrtz(xa[2]*L2E2, xa[3]*L2E2);
            dx[2]=pkrtz(xb[0]*L2E2, xb[1]*L2E2); dx[3]=pkrtz(xb[2]*L2E2, xb[3]*L2E2);
            whA[m][T] = __builtin_bit_cast(f16x8, dw);
            wxA[m][T] = __builtin_bit_cast(f16x8, dx);
        }
    }
    // combined bias (prescaled), C-frag layout: reg r <-> ch 16m+4g+r
    f32x4 biasf[4];
    #pragma unroll
    for (int m = 0; m < 4; ++m) {
        f32x4 b1 = *(const f32x4*)(bh + 16*m + 4*g);
        f32x4 b2 = *(const f32x4*)(bx + 16*m + 4*g);
        biasf[m] = (b1 + b2) * L2E2;
    }

    // ---- h frags for t=0 (B-frag: col=n, k=8g+e (+32 for T1)) ----
    f16x8 fh0, fh1;
    {
        const float* hr = h0 + (size_t)(R0 + nc) * HD + 8*g;
        f32x4 a0 = *(const f32x4*)hr,        a1 = *(const f32x4*)(hr + 4);
        f32x4 b0 = *(const f32x4*)(hr + 32), b1 = *(const f32x4*)(hr + 36);
        u32x4 c0, c1;
        c0[0]=pkrtz(a0[0],a0[1]); c0[1]=pkrtz(a0[2],a0[3]); c0[2]=pkrtz(a1[0],a1[1]); c0[3]=pkrtz(a1[2],a1[3]);
        c1[0]=pkrtz(b0[0],b0[1]); c1[1]=pkrtz(b0[2],b0[3]); c1[2]=pkrtz(b1[0],b1[1]); c1[3]=pkrtz(b1[2],b1[3]);
        fh0 = __builtin_bit_cast(f16x8, c0);
        fh1 = __builtin_bit_cast(f16x8, c1);
    }

    // ---- xp(0) = (Wx*x(0) + bias), prescaled ----
    f32x4 xp[4];
    {
        const float* xr = x + xoff;
        f32x4 a0 = *(const f32x4*)xr,        a1 = *(const f32x4*)(xr + 4);
        f32x4 b0 = *(const f32x4*)(xr + 32), b1 = *(const f32x4*)(xr + 36);
        u32x4 c0, c1;
        c0[0]=pkrtz(a0[0],a0[1]); c0[1]=pkrtz(a0[2],a0[3]); c0[2]=pkrtz(a1[0],a1[1]); c0[3]=pkrtz(a1[2],a1[3]);
        c1[0]=pkrtz(b0[0],b0[1]); c1[1]=pkrtz(b0[2],b0[3]); c1[2]=pkrtz(b1[0],b1[1]); c1[3]=pkrtz(b1[2],b1[3]);
        f16x8 fx0 = __builtin_bit_cast(f16x8, c0);
        f16x8 fx1 = __builtin_bit_cast(f16x8, c1);
        #pragma unroll
        for (int m = 0; m < 4; ++m) {
            f32x4 tq = __builtin_amdgcn_mfma_f32_16x16x32_f16(wxA[m][0], fx0, biasf[m], 0, 0, 0);
            xp[m]    = __builtin_amdgcn_mfma_f32_16x16x32_f16(wxA[m][1], fx1, tq,       0, 0, 0);
        }
    }

    // ---- x register ring (depth 4): slot s <- x(s); preload 1..3 ----
    f32x4 ring[4][4];
    #pragma unroll
    for (int s = 1; s <= 3; ++s) {
        const f32x4* xs = (const f32x4*)(x + (size_t)s * BH + xoff);
        ring[s][0] = xs[0]; ring[s][1] = xs[1]; ring[s][2] = xs[8]; ring[s][3] = xs[9];
    }

    // bpermute addrs (fallback exchange): src lane = 16*(2*(g&1)+c) + n
    const int addr0 = ((2*(g&1) + 0) * 16 + n) << 2;
    const int addr1 = ((2*(g&1) + 1) * 16 + n) << 2;

    // ================= main loop (templated on exchange mode) =================
    auto mainloop = [&](auto mc) {
        constexpr int  MODE = decltype(mc)::value;
        constexpr bool PERM = MODE < 4;
        constexpr bool S1   = (MODE == 2) || (MODE == 3);  // hw swaps dst.lo <-> src.hi
        constexpr bool RF   = (MODE == 1) || (MODE == 3);  // builtin returns {src',dst'}

        // canonical swaps: out0 = updated vdst, out1 = updated vsrc
        auto cswap32 = [&](uint32_t a, uint32_t b, uint32_t& o0, uint32_t& o1) {
#if HAVE_PERMLANE
            auto r = __builtin_amdgcn_permlane32_swap(a, b, false, false);
            o0 = RF ? (uint32_t)r[1] : (uint32_t)r[0];
            o1 = RF ? (uint32_t)r[0] : (uint32_t)r[1];
#else
            o0 = a; o1 = b;
#endif
        };
        auto cswap16 = [&](uint32_t a, uint32_t b, uint32_t& o0, uint32_t& o1) {
#if HAVE_PERMLANE
            auto r = __builtin_amdgcn_permlane16_swap(a, b, false, false);
            o0 = RF ? (uint32_t)r[1] : (uint32_t)r[0];
            o1 = RF ? (uint32_t)r[0] : (uint32_t)r[1];
#else
            o0 = a; o1 = b;
#endif
        };

        for (int tb = 0; tb < SEQ; tb += 4) {
            #pragma unroll
            for (int u = 0; u < 4; ++u) {
                const int t  = tb + u;
                const int sc = (u + 1) & 3;         // slot holding x(t+1)

                // --- refill ring slot u with x(t+4) (fire & forget) ---
                {
                    int tl = t + 4; tl = tl > SEQ - 1 ? SEQ - 1 : tl;
                    const f32x4* xs = (const f32x4*)(x + (size_t)tl * BH + xoff);
                    ring[u][0] = xs[0]; ring[u][1] = xs[1]; ring[u][2] = xs[8]; ring[u][3] = xs[9];
                }

                // --- critical chain: acc = Wh*h(t) + xp(t) (2-deep MFMA per tile) ---
                f32x4 acc[4];
                #pragma unroll
                for (int m = 0; m < 4; ++m) {
                    f32x4 hp = __builtin_amdgcn_mfma_f32_16x16x32_f16(whA[m][0], fh0, xp[m], 0, 0, 0);
                    acc[m]   = __builtin_amdgcn_mfma_f32_16x16x32_f16(whA[m][1], fh1, hp,    0, 0, 0);
                }

                // --- off-chain: xp(t+1) from ring (loaded 3-4 steps ago) ---
                {
                    f32x4 r0v = ring[sc][0], r1v = ring[sc][1], r2v = ring[sc][2], r3v = ring[sc][3];
                    u32x4 c0, c1;
                    c0[0]=pkrtz(r0v[0],r0v[1]); c0[1]=pkrtz(r0v[2],r0v[3]); c0[2]=pkrtz(r1v[0],r1v[1]); c0[3]=pkrtz(r1v[2],r1v[3]);
                    c1[0]=pkrtz(r2v[0],r2v[1]); c1[1]=pkrtz(r2v[2],r2v[3]); c1[2]=pkrtz(r3v[0],r3v[1]); c1[3]=pkrtz(r3v[2],r3v[3]);
                    f16x8 fx0 = __builtin_bit_cast(f16x8, c0);
                    f16x8 fx1 = __builtin_bit_cast(f16x8, c1);
                    #pragma unroll
                    for (int m = 0; m < 4; ++m) {
                        f32x4 tq = __builtin_amdgcn_mfma_f32_16x16x32_f16(wxA[m][0], fx0, biasf[m], 0, 0, 0);
                        xp[m]    = __builtin_amdgcn_mfma_f32_16x16x32_f16(wxA[m][1], fx1, tq,       0, 0, 0);
                    }
                }

                // --- tanh + pack: wv[m][p] = f16 pair (ch 16m+4g+2p, +1) ---
                f32x4 tvv[4]; uint32_t wv[4][2];
                #pragma unroll
                for (int m = 0; m < 4; ++m) {
                    f32x4 a = acc[m], tv;
                    #pragma unroll
                    for (int r = 0; r < 4; ++r) tv[r] = tanh_scaled(a[r]);
                    tvv[m] = tv;
                    wv[m][0] = pkrtz(tv[0], tv[1]);
                    wv[m][1] = pkrtz(tv[2], tv[3]);
                }

                // --- exchange: C-layout -> B-frags for t+1 (pure cross-lane, no LDS) ---
                // frag[T] dword q = w[2T+(g>>1)][q&1] from lane 16*(2*(g&1)+(q>>1))+n
                #pragma unroll
                for (int T = 0; T < 2; ++T) {
                    u32x4 fd;
                    if constexpr (PERM) {
                        #pragma unroll
                        for (int p = 0; p < 2; ++p) {
                            uint32_t Ra, Rb, F0, F1;
                            if constexpr (!S1) cswap32(wv[2*T][p], wv[2*T+1][p], Ra, Rb);   // (R0,R1)
                            else               cswap32(wv[2*T+1][p], wv[2*T][p], Rb, Ra);   // (R1,R0)
                            if constexpr (!S1) cswap16(Ra, Rb, F0, F1);                      // (Fu0,Fu1)
                            else               cswap16(Rb, Ra, F1, F0);                      // (Fu1,Fu0)
                            fd[p]     = F0;   // q = 0+p
                            fd[2 + p] = F1;   // q = 2+p
                        }
                    } else {
                        #pragma unroll
                        for (int q = 0; q < 4; ++q) {
                            int ad = (q >> 1) ? addr1 : addr0;
                            int va = __builtin_amdgcn_ds_bpermute(ad, (int)wv[2*T][q & 1]);
                            int vb = __builtin_amdgcn_ds_bpermute(ad, (int)wv[2*T+1][q & 1]);
                            fd[q] = (uint32_t)((g >> 1) ? vb : va);
                        }
                    }
                    if (T == 0) fh0 = __builtin_bit_cast(f16x8, fd);
                    else        fh1 = __builtin_bit_cast(f16x8, fd);
                }

                // --- off-chain stores ---
                if (n < RPW) {
                    float* dst = out + (size_t)t * BH + (size_t)(R0 + n) * HD + 4*g;
                    #pragma unroll
                    for (int m = 0; m < 4; ++m) *(f32x4*)(dst + 16*m) = tvv[m];
                    if (t == SEQ - 1) {
                        float* dl = out + (size_t)SEQ * BH + (size_t)(R0 + n) * HD + 4*g;
                        #pragma unroll
                        for (int m = 0; m < 4; ++m) *(f32x4*)(dl + 16*m) = tvv[m];
                    }
                }
            }
        }
    };

    // ---- detect permlane swap semantics with a 1-op probe, then dispatch ----
#if HAVE_PERMLANE
    {
        auto pr = __builtin_amdgcn_permlane32_swap((uint32_t)lane, (uint32_t)lane + 1000u, false, false);
        int v = __builtin_amdgcn_readfirstlane((int)pr[0]);
        if      (v == 0)    mainloop(IC<0>{});   // dst.hi<->src.lo, ret {dst',src'}
        else if (v == 32)   mainloop(IC<1>{});   // dst.hi<->src.lo, ret {src',dst'}
        else if (v == 1032) mainloop(IC<2>{});   // dst.lo<->src.hi, ret {dst',src'}
        else if (v == 1000) mainloop(IC<3>{});   // dst.lo<->src.hi, ret {src',dst'}
        else                mainloop(IC<4>{});   // unknown -> ds_bpermute fallback
    }
#else
    mainloop(IC<4>{});
#endif
}

extern "C" void kernel_launch(void* const* d_in, const int* in_sizes, int n_in,
                              void* d_out, int out_size, void* d_ws, size_t ws_size,
                              hipStream_t stream) {
    const float* x  = (const float*)d_in[0];
    const float* h  = (const float*)d_in[1];
    const float* Wx = (const float*)d_in[2];
    const float* bx = (const float*)d_in[3];
    const float* Wh = (const float*)d_in[4];
    const float* bh = (const float*)d_in[5];
    float* out = (float*)d_out;

    rnn_kernel<<<dim3(NB / RPW), dim3(64), 0, stream>>>(x, h, Wx, bx, Wh, bh, out);
}